// Round 3
// baseline (118.013 us; speedup 1.0000x reference)
//
#include <hip/hip_runtime.h>
#include <hip/hip_bf16.h>

// RBF collocation, N=6144. G[i,j] = exp(-0.5*||c_j - p_i||^2),
// 17 outputs: out_o[i] = sum_j G[i,j] * P_o(dx,dz,dt) * v_k[j],
// dx = cx_j - x_i, P in {dx,dz,dt, dx^2-1, dz^2-1} (closed-form nested JVPs).
// Output order: dudx,dudz,dudt(v3) | dwdx,dwdz,dwdt(v4) | dbdx,dbdz,dbdt(v2)
//             | dpdx,dpdz(v1) | d2u2x,d2u2z(v3) | d2w2x,d2w2z(v4) | d2b2x,d2b2z(v2)
//
// Round-3 finding: inputs fp32 (round-1 bf16 misread -> NaN), output fp32
// (round-2 bf16 writes misread by harness as fp32 -> ~2x-max error).
// Input dtype still auto-sniffed for safety; OUTPUT IS WRITTEN AS FLOAT32.

#define NPTS 6144
#define NOUT 17
#define SPLIT 8               // j-chunks per row-group
#define JC (NPTS / SPLIT)     // 768 j per block
#define SUBJ (JC / 4)         // 192 j per wave
#define ROWG 64               // rows per block (one per lane)

// ws layout (float units):
#define PART_OFF 0
#define PART_SZ (SPLIT * NOUT * NPTS)        // 835584 floats
#define PACK_OFF (PART_OFF + PART_SZ)        // byte off 3342336, 16B aligned
#define PACK_SZ (NPTS * 8)                   // 49152 floats
#define ROWS_OFF (PACK_OFF + PACK_SZ)
#define ROWS_SZ (3 * NPTS)
#define FLAG_OFF (ROWS_OFF + ROWS_SZ)

__device__ __forceinline__ float ldin(const void* p, int i, bool f32) {
  return f32 ? ((const float*)p)[i]
             : __bfloat162float(((const __hip_bfloat16*)p)[i]);
}

// Sniff input dtype from the bit pattern of x as uint16[NPTS]. fp32 data ->
// ~45% of low-halves have garbage bf16 exponents; bf16 data -> ~0. flag=1 => fp32.
__global__ void rbf_detect(const unsigned short* __restrict__ xu,
                           int* __restrict__ flag) {
  __shared__ int cnt[256];
  int c = 0;
  for (int i = threadIdx.x; i < NPTS; i += 256) {
    const unsigned short u = xu[i];
    const int e = (u >> 7) & 0xFF;
    if ((u & 0x7FFF) == 0) c++;
    else if (e >= 143 || e == 0) c++;
  }
  cnt[threadIdx.x] = c;
  __syncthreads();
  for (int s = 128; s > 0; s >>= 1) {
    if ((int)threadIdx.x < s) cnt[threadIdx.x] += cnt[threadIdx.x + s];
    __syncthreads();
  }
  if (threadIdx.x == 0) *flag = (cnt[0] > 512) ? 1 : 0;
}

__global__ void rbf_prep(const void* __restrict__ xp, const void* __restrict__ zp,
                         const void* __restrict__ tp, const void* __restrict__ cp,
                         const void* __restrict__ v1p, const void* __restrict__ v2p,
                         const void* __restrict__ v3p, const void* __restrict__ v4p,
                         float4* __restrict__ packed, float* __restrict__ rows,
                         const int* __restrict__ flag) {
  const int j = blockIdx.x * blockDim.x + threadIdx.x;
  const bool f32 = (*flag != 0);            // wave-uniform branch
  if (j < NPTS) {
    rows[j]            = ldin(xp, j, f32);
    rows[NPTS + j]     = ldin(zp, j, f32);
    rows[2 * NPTS + j] = ldin(tp, j, f32);
    packed[2 * j] = make_float4(ldin(cp, 3 * j, f32), ldin(cp, 3 * j + 1, f32),
                                ldin(cp, 3 * j + 2, f32), ldin(v1p, j, f32));
    packed[2 * j + 1] = make_float4(ldin(v2p, j, f32), ldin(v3p, j, f32),
                                    ldin(v4p, j, f32), 0.f);
  }
}

__global__ __launch_bounds__(256) void rbf_main(
    const float* __restrict__ rows,
    const float4* __restrict__ packed,   // wave-uniform j reads -> sgpr broadcast
    float* __restrict__ part) {
  __shared__ float red[3][NOUT][ROWG];

  const int s    = blockIdx.x % SPLIT;
  const int rg   = blockIdx.x / SPLIT;
  const int w    = threadIdx.x >> 6;
  const int lane = threadIdx.x & 63;
  const int row  = rg * ROWG + lane;

  const float xi = rows[row];
  const float zi = rows[NPTS + row];
  const float ti = rows[2 * NPTS + row];

  float acc[NOUT];
#pragma unroll
  for (int o = 0; o < NOUT; ++o) acc[o] = 0.f;

  const int j0 = s * JC + w * SUBJ;
#pragma unroll 4
  for (int k = 0; k < SUBJ; ++k) {
    const float4 a = packed[2 * (j0 + k)];      // cx, cz, ct, v1
    const float4 b = packed[2 * (j0 + k) + 1];  // v2, v3, v4, -
    const float dx = a.x - xi;
    const float dz = a.y - zi;
    const float dt = a.z - ti;
    const float r2 = fmaf(dx, dx, fmaf(dz, dz, dt * dt));
    const float G  = __expf(-0.5f * r2);
    const float g1 = G * a.w;
    const float g2 = G * b.x;
    const float g3 = G * b.y;
    const float g4 = G * b.z;
    const float sx = fmaf(dx, dx, -1.f);
    const float sz = fmaf(dz, dz, -1.f);
    acc[0]  = fmaf(g3, dx, acc[0]);
    acc[1]  = fmaf(g3, dz, acc[1]);
    acc[2]  = fmaf(g3, dt, acc[2]);
    acc[3]  = fmaf(g4, dx, acc[3]);
    acc[4]  = fmaf(g4, dz, acc[4]);
    acc[5]  = fmaf(g4, dt, acc[5]);
    acc[6]  = fmaf(g2, dx, acc[6]);
    acc[7]  = fmaf(g2, dz, acc[7]);
    acc[8]  = fmaf(g2, dt, acc[8]);
    acc[9]  = fmaf(g1, dx, acc[9]);
    acc[10] = fmaf(g1, dz, acc[10]);
    acc[11] = fmaf(g3, sx, acc[11]);
    acc[12] = fmaf(g3, sz, acc[12]);
    acc[13] = fmaf(g4, sx, acc[13]);
    acc[14] = fmaf(g4, sz, acc[14]);
    acc[15] = fmaf(g2, sx, acc[15]);
    acc[16] = fmaf(g2, sz, acc[16]);
  }

  if (w > 0) {
#pragma unroll
    for (int o = 0; o < NOUT; ++o) red[w - 1][o][lane] = acc[o];
  }
  __syncthreads();
  if (w == 0) {
#pragma unroll
    for (int o = 0; o < NOUT; ++o) {
      const float v = acc[o] + red[0][o][lane] + red[1][o][lane] + red[2][o][lane];
      part[(s * NOUT + o) * NPTS + row] = v;
    }
  }
}

__global__ void rbf_finish(const float* __restrict__ part,
                           float* __restrict__ out, int n) {
  const int f = blockIdx.x * blockDim.x + threadIdx.x;
  if (f < n) {
    float sum = 0.f;
#pragma unroll
    for (int s = 0; s < SPLIT; ++s) sum += part[s * (NOUT * NPTS) + f];
    out[f] = sum;   // OUTPUT IS FP32 (reference output dtype)
  }
}

extern "C" void kernel_launch(void* const* d_in, const int* in_sizes, int n_in,
                              void* d_out, int out_size, void* d_ws, size_t ws_size,
                              hipStream_t stream) {
  float*  ws     = (float*)d_ws;
  float*  part   = ws + PART_OFF;
  float4* packed = (float4*)(ws + PACK_OFF);
  float*  rows   = ws + ROWS_OFF;
  int*    flag   = (int*)(ws + FLAG_OFF);

  rbf_detect<<<1, 256, 0, stream>>>((const unsigned short*)d_in[0], flag);

  rbf_prep<<<(NPTS + 255) / 256, 256, 0, stream>>>(
      d_in[0], d_in[1], d_in[2], d_in[3], d_in[4], d_in[5], d_in[6], d_in[7],
      packed, rows, flag);

  rbf_main<<<(NPTS / ROWG) * SPLIT, 256, 0, stream>>>(rows, (const float4*)packed,
                                                      part);

  const int n = NOUT * NPTS;  // == out_size
  rbf_finish<<<(n + 255) / 256, 256, 0, stream>>>(part, (float*)d_out, n);
}

// Round 4
// 101.893 us; speedup vs baseline: 1.1582x; 1.1582x over previous
//
#include <hip/hip_runtime.h>
#include <hip/hip_bf16.h>

// RBF collocation, N=6144. G[i,j] = exp(-0.5*||c_j - p_i||^2),
// 17 outputs: out_o[i] = sum_j G[i,j] * P_o(dx,dz,dt) * v_k[j],
// dx = cx_j - x_i, P in {dx,dz,dt, dx^2-1, dz^2-1} (closed-form nested JVPs).
// Output order: dudx,dudz,dudt(v3) | dwdx,dwdz,dwdt(v4) | dbdx,dbdz,dbdt(v2)
//             | dpdx,dpdz(v1) | d2u2x,d2u2z(v3) | d2w2x,d2w2z(v4) | d2b2x,d2b2z(v2)
//
// Dtypes PROVEN in rounds 1-3: inputs fp32, output fp32. Detect kernel dropped.
// R4 changes: SPLIT 8->16 (occupancy 3->6 blocks/CU), readfirstlane-forced
// scalar s_load for wave-uniform j-data, exp2 constant folding.

#define NPTS 6144
#define NOUT 17
#define SPLIT 16              // j-chunks per row-group
#define JC (NPTS / SPLIT)     // 384 j per block
#define SUBJ (JC / 4)         // 96 j per wave
#define ROWG 64               // rows per block (one per lane)

// ws layout (float units):
#define PART_SZ (SPLIT * NOUT * NPTS)   // 1671168 floats = 6.68 MB
#define PACK_OFF PART_SZ                // byte offset 6684672, 16B aligned
#define PACK_SZ (NPTS * 8)

#if defined(__has_builtin) && __has_builtin(__builtin_amdgcn_exp2f)
#define EXP2F(x) __builtin_amdgcn_exp2f(x)
#else
#define EXP2F(x) __expf((x) * 0.6931471805599453f)
#endif

__global__ void rbf_prep(const float* __restrict__ cp,
                         const float* __restrict__ v1p,
                         const float* __restrict__ v2p,
                         const float* __restrict__ v3p,
                         const float* __restrict__ v4p,
                         float4* __restrict__ packed) {
  const int j = blockIdx.x * blockDim.x + threadIdx.x;
  if (j < NPTS) {
    packed[2 * j]     = make_float4(cp[3 * j], cp[3 * j + 1], cp[3 * j + 2], v1p[j]);
    packed[2 * j + 1] = make_float4(v2p[j], v3p[j], v4p[j], 0.f);
  }
}

__global__ __launch_bounds__(256) void rbf_main(
    const float* __restrict__ xp, const float* __restrict__ zp,
    const float* __restrict__ tp,
    const float4* __restrict__ packed,
    float* __restrict__ part) {
  __shared__ float red[3][NOUT][ROWG];

  const int s    = blockIdx.x & (SPLIT - 1);
  const int rg   = blockIdx.x / SPLIT;
  const int w    = threadIdx.x >> 6;
  const int lane = threadIdx.x & 63;
  const int row  = rg * ROWG + lane;

  const float xi = xp[row];
  const float zi = zp[row];
  const float ti = tp[row];

  float acc[NOUT];
#pragma unroll
  for (int o = 0; o < NOUT; ++o) acc[o] = 0.f;

  // Wave-uniform chunk base, forced into an SGPR so j-data loads compile to
  // s_load_dwordx4 (scalar pipe) instead of per-lane global_load + addr VALU.
  const int j0u = __builtin_amdgcn_readfirstlane(s * JC + w * SUBJ);
  const float4* __restrict__ pb = packed + 2 * j0u;

#pragma unroll 4
  for (int k = 0; k < SUBJ; ++k) {
    const float4 a = pb[2 * k];      // cx, cz, ct, v1
    const float4 b = pb[2 * k + 1];  // v2, v3, v4, -
    const float dx = a.x - xi;
    const float dz = a.y - zi;
    const float dt = a.z - ti;
    const float r2 = fmaf(dx, dx, fmaf(dz, dz, dt * dt));
    const float G  = EXP2F(-0.7213475204444817f * r2);  // exp(-0.5*r2)
    const float g1 = G * a.w;
    const float g2 = G * b.x;
    const float g3 = G * b.y;
    const float g4 = G * b.z;
    const float sx = fmaf(dx, dx, -1.f);
    const float sz = fmaf(dz, dz, -1.f);
    acc[0]  = fmaf(g3, dx, acc[0]);
    acc[1]  = fmaf(g3, dz, acc[1]);
    acc[2]  = fmaf(g3, dt, acc[2]);
    acc[3]  = fmaf(g4, dx, acc[3]);
    acc[4]  = fmaf(g4, dz, acc[4]);
    acc[5]  = fmaf(g4, dt, acc[5]);
    acc[6]  = fmaf(g2, dx, acc[6]);
    acc[7]  = fmaf(g2, dz, acc[7]);
    acc[8]  = fmaf(g2, dt, acc[8]);
    acc[9]  = fmaf(g1, dx, acc[9]);
    acc[10] = fmaf(g1, dz, acc[10]);
    acc[11] = fmaf(g3, sx, acc[11]);
    acc[12] = fmaf(g3, sz, acc[12]);
    acc[13] = fmaf(g4, sx, acc[13]);
    acc[14] = fmaf(g4, sz, acc[14]);
    acc[15] = fmaf(g2, sx, acc[15]);
    acc[16] = fmaf(g2, sz, acc[16]);
  }

  if (w > 0) {
#pragma unroll
    for (int o = 0; o < NOUT; ++o) red[w - 1][o][lane] = acc[o];
  }
  __syncthreads();
  if (w == 0) {
#pragma unroll
    for (int o = 0; o < NOUT; ++o) {
      const float v = acc[o] + red[0][o][lane] + red[1][o][lane] + red[2][o][lane];
      part[(s * NOUT + o) * NPTS + row] = v;
    }
  }
}

__global__ void rbf_finish(const float* __restrict__ part,
                           float* __restrict__ out, int n) {
  const int f = blockIdx.x * blockDim.x + threadIdx.x;
  if (f < n) {
    float sum = 0.f;
#pragma unroll
    for (int s = 0; s < SPLIT; ++s) sum += part[s * (NOUT * NPTS) + f];
    out[f] = sum;   // fp32 output
  }
}

extern "C" void kernel_launch(void* const* d_in, const int* in_sizes, int n_in,
                              void* d_out, int out_size, void* d_ws, size_t ws_size,
                              hipStream_t stream) {
  const float* xp  = (const float*)d_in[0];
  const float* zp  = (const float*)d_in[1];
  const float* tp  = (const float*)d_in[2];
  const float* cp  = (const float*)d_in[3];
  const float* v1p = (const float*)d_in[4];
  const float* v2p = (const float*)d_in[5];
  const float* v3p = (const float*)d_in[6];
  const float* v4p = (const float*)d_in[7];

  float*  ws     = (float*)d_ws;
  float*  part   = ws;
  float4* packed = (float4*)(ws + PACK_OFF);

  rbf_prep<<<(NPTS + 255) / 256, 256, 0, stream>>>(cp, v1p, v2p, v3p, v4p, packed);

  rbf_main<<<(NPTS / ROWG) * SPLIT, 256, 0, stream>>>(xp, zp, tp,
                                                      (const float4*)packed, part);

  const int n = NOUT * NPTS;  // == out_size == 104448
  rbf_finish<<<(n + 255) / 256, 256, 0, stream>>>(part, (float*)d_out, n);
}